// Round 6
// baseline (250.820 us; speedup 1.0000x reference)
//
#include <hip/hip_runtime.h>
#include <hip/hip_bf16.h>

#define B_  16384
#define I_  512
#define H1_ 256
#define H2_ 128
#define E_  8
#define T_  2

typedef __attribute__((ext_vector_type(8))) short short8;
typedef __attribute__((ext_vector_type(4))) float float4_t;

__device__ inline unsigned short f2bf(float f) {
    union { float f; unsigned u; } v; v.f = f;
    unsigned r = v.u + 0x7FFFu + ((v.u >> 16) & 1u);
    return (unsigned short)(r >> 16);
}

// async global->LDS, 16B per lane. LDS dest = wave-uniform base + lane*16.
__device__ inline void async_copy16(const unsigned short* g, unsigned short* l) {
    __builtin_amdgcn_global_load_lds(
        (const __attribute__((address_space(1))) void*)g,
        (__attribute__((address_space(3))) void*)l,
        16, 0, 0);
}

// ================= prep + gates megakernel (one dispatch) =================
// Verified structure; only change: Wg staging via float4 (was scalar f32).
__global__ void prep_gates_kernel(const float* __restrict__ x,
                                  unsigned short* __restrict__ xb,
                                  const float* __restrict__ W1,
                                  unsigned short* __restrict__ w1t,
                                  const float* __restrict__ W2,
                                  unsigned short* __restrict__ w2t,
                                  const float* __restrict__ Wg,
                                  const float* __restrict__ bg,
                                  float* __restrict__ gates) {
    __shared__ __align__(16) char smem[16 * 520 * 2 + 4 * 16 * 16 * 4];  // 20.6 KB
    int bid = blockIdx.x;
    int t = threadIdx.x;

    if (bid < 1024) {
        unsigned short* wgtL = (unsigned short*)smem;          // [16][520] padded
        float (*red)[16][16] = (float (*)[16][16])(smem + 16 * 520 * 2);
#pragma unroll
        for (int j = 0; j < 8; ++j) {
            int idx4 = j * 256 + t;                 // 0..2047 float4s of Wg
            float4_t wv = ((const float4_t*)Wg)[idx4];
            int e0   = (idx4 & 1) * 4;
            int i    = (idx4 >> 1) & 511;
            int task = idx4 >> 10;
#pragma unroll
            for (int c = 0; c < 4; ++c)
                wgtL[(task * 8 + e0 + c) * 520 + i] = f2bf(wv[c]);
        }
        __syncthreads();

        int w = t >> 6, lane = t & 63;
        int col = lane & 15, quad = lane >> 4;
        int b0 = bid * 16;
        int k0 = w * 128;
        const float* xr = x + (size_t)(b0 + col) * I_ + k0 + quad * 8;
        unsigned short* xw = xb + (size_t)(b0 + col) * I_ + k0 + quad * 8;
        const unsigned short* bL = &wgtL[col * 520 + k0 + quad * 8];
        float4_t acc = {0.f, 0.f, 0.f, 0.f};
#pragma unroll
        for (int ks = 0; ks < 128; ks += 32) {
            float4_t xa = *(const float4_t*)(xr + ks);
            float4_t xc = *(const float4_t*)(xr + ks + 4);
            short8 a;
            a[0] = (short)f2bf(xa[0]); a[1] = (short)f2bf(xa[1]);
            a[2] = (short)f2bf(xa[2]); a[3] = (short)f2bf(xa[3]);
            a[4] = (short)f2bf(xc[0]); a[5] = (short)f2bf(xc[1]);
            a[6] = (short)f2bf(xc[2]); a[7] = (short)f2bf(xc[3]);
            *(short8*)(xw + ks) = a;
            short8 b = *(const short8*)(bL + ks);
            acc = __builtin_amdgcn_mfma_f32_16x16x32_bf16(a, b, acc, 0, 0, 0);
        }
#pragma unroll
        for (int p = 0; p < 4; ++p)
            red[w][quad * 4 + p][col] = acc[p];
        __syncthreads();
        int r = t >> 4, te = t & 15;
        float v = red[0][r][te] + red[1][r][te] + red[2][r][te] + red[3][r][te] + bg[te];
        float m = v;
        m = fmaxf(m, __shfl_xor(m, 1));
        m = fmaxf(m, __shfl_xor(m, 2));
        m = fmaxf(m, __shfl_xor(m, 4));
        float ev = __expf(v - m);
        float s = ev;
        s += __shfl_xor(s, 1);
        s += __shfl_xor(s, 2);
        s += __shfl_xor(s, 4);
        gates[(size_t)te * B_ + b0 + r] = ev / s;
    } else {
        float (*tile)[33] = (float (*)[33])smem;
        const float* in; unsigned short* outp; int R, C, e, r0, c0;
        if (bid < 2048) {
            int tl = bid - 1024;               // 8 e x 16 rblk x 8 cblk
            e = tl >> 7; int rem = tl & 127;
            R = I_; C = H1_;
            r0 = (rem >> 3) * 32; c0 = (rem & 7) * 32;
            in = W1; outp = w1t;
        } else {
            int tl = bid - 2048;               // 8 e x 8 rblk x 4 cblk
            e = tl >> 5; int rem = tl & 31;
            R = H1_; C = H2_;
            r0 = (rem >> 2) * 32; c0 = (rem & 3) * 32;
            in = W2; outp = w2t;
        }
        const float* inp = in + (size_t)e * R * C;
        unsigned short* op = outp + (size_t)e * R * C;
        int tx = t & 31, ty = t >> 5;          // (32, 8)
#pragma unroll
        for (int j = 0; j < 32; j += 8)
            tile[ty + j][tx] = inp[(size_t)(r0 + ty + j) * C + c0 + tx];
        __syncthreads();
#pragma unroll
        for (int j = 0; j < 32; j += 8)
            op[(size_t)(c0 + ty + j) * R + r0 + tx] = f2bf(tile[tx][ty + j]);
    }
}

// ---------------- layer 1 grouped GEMM: h[e] = relu(xb * w1t[e]^T + b1[e]) bf16 ----------------
// r0's verified 128x128 / 256-thread structure, with LDS trimmed 34816 -> 32768 B
// so 5 blocks/CU fit (5 x 32768 = 163840 = full 160 KiB). Epilogue restages C in
// two 64-row half-passes (64 x stride136 = 17.4 KB, aliased onto As after the
// final K-loop barrier). Inner loop byte-identical to the verified kernel.
__global__ __launch_bounds__(256, 5)
void gemm_relu_kernel(const unsigned short* __restrict__ A, size_t aSE,
                      const unsigned short* __restrict__ Bt, size_t bSE,
                      const float* __restrict__ bias, int biasSE,
                      unsigned short* __restrict__ C, size_t cSE,
                      int K, int lda, int ldb, int ldc) {
    __shared__ __align__(16) unsigned short smem[16384];   // 32 KB: As|Bs
    unsigned short* As = smem;                    // 128*64
    unsigned short* Bs = smem + 8192;             // 128*64
    int e = blockIdx.z;
    const unsigned short* Ae = A + (size_t)e * aSE;
    const unsigned short* Be = Bt + (size_t)e * bSE;
    const float* biasE = bias + (size_t)e * biasSE;
    unsigned short* Ce = C + (size_t)e * cSE;
    int m0 = blockIdx.x * 128, n0 = blockIdx.y * 128;
    int t = threadIdx.x, w = t >> 6, lane = t & 63;
    int col = lane & 15, quad = lane >> 4;
    int wm = (w & 1) * 64, wn = (w >> 1) * 64;

    float4_t acc[4][4];
#pragma unroll
    for (int mi = 0; mi < 4; ++mi)
#pragma unroll
        for (int ni = 0; ni < 4; ++ni)
            acc[mi][ni] = (float4_t){0.f, 0.f, 0.f, 0.f};

    int rT = t >> 3;
    int gk = (((t & 7) ^ (rT & 7))) * 8;
    const unsigned short* aG = Ae + (size_t)(m0 + rT) * lda + gk;
    const unsigned short* bG = Be + (size_t)(n0 + rT) * ldb + gk;
    unsigned short* aL = As + (size_t)w * 64 * 8;
    unsigned short* bL = Bs + (size_t)w * 64 * 8;

    for (int k0 = 0; k0 < K; k0 += 64) {
#pragma unroll
        for (int j = 0; j < 4; ++j) {
            async_copy16(aG + (size_t)j * 32 * lda + k0, aL + j * 2048);
            async_copy16(bG + (size_t)j * 32 * ldb + k0, bL + j * 2048);
        }
        __syncthreads();
#pragma unroll
        for (int kk = 0; kk < 64; kk += 32) {
            int q = (kk >> 3) + quad;
            short8 af[4], bf[4];
#pragma unroll
            for (int mi = 0; mi < 4; ++mi) {
                int r = wm + mi * 16 + col;
                af[mi] = *(const short8*)&As[r * 64 + ((q ^ (r & 7)) * 8)];
            }
#pragma unroll
            for (int ni = 0; ni < 4; ++ni) {
                int r = wn + ni * 16 + col;
                bf[ni] = *(const short8*)&Bs[r * 64 + ((q ^ (r & 7)) * 8)];
            }
#pragma unroll
            for (int mi = 0; mi < 4; ++mi)
#pragma unroll
                for (int ni = 0; ni < 4; ++ni)
                    acc[mi][ni] = __builtin_amdgcn_mfma_f32_16x16x32_bf16(af[mi], bf[ni], acc[mi][ni], 0, 0, 0);
        }
        __syncthreads();
    }
    // epilogue: bias+relu -> bf16 in two 64-row half-passes (Ct aliases As, safe
    // after the loop's final barrier). Waves with (w&1)==half own rows half*64..+63.
    unsigned short* Ct = smem;   // 64 rows x stride 136 = 17408 B
#pragma unroll
    for (int half = 0; half < 2; ++half) {
        if ((w & 1) == half) {
#pragma unroll
            for (int ni = 0; ni < 4; ++ni) {
                int c = wn + ni * 16 + col;
                float bv = biasE[n0 + c];
#pragma unroll
                for (int mi = 0; mi < 4; ++mi) {
                    int rl = mi * 16 + quad * 4;     // local row within the half
#pragma unroll
                    for (int p = 0; p < 4; ++p) {
                        float v = acc[mi][ni][p] + bv;
                        v = v > 0.f ? v : 0.f;
                        Ct[(rl + p) * 136 + c] = f2bf(v);
                    }
                }
            }
        }
        __syncthreads();
        int rr = t >> 4, sl = t & 15;
#pragma unroll
        for (int pass = 0; pass < 4; ++pass) {
            int row = pass * 16 + rr;
            short8 vv = *(const short8*)&Ct[row * 136 + sl * 8];
            *(short8*)&Ce[(size_t)(m0 + half * 64 + row) * ldc + n0 + sl * 8] = vv;
        }
        __syncthreads();
    }
}

// ---------------- fused layer2 + gated combine: ring-3, depth-1 prefetch ----------------
// UNCHANGED (verified r4). 64 rows x full H2 per block, grid 256, 76 KB -> 2 blocks/CU.
// Per chunk cid: [stage(cid+1) -> slot (cid+1)%3] [vmcnt(3)] [s_barrier] [compute slot cid%3]
// Race-free (R=3 >= D+2 with D=1).
__global__ __launch_bounds__(512, 4)
void fused_l2_combine_kernel(const unsigned short* __restrict__ h,
                             const unsigned short* __restrict__ w2t,
                             const float* __restrict__ b2,
                             const float* __restrict__ gates,
                             float* __restrict__ out) {
    __shared__ __align__(16) unsigned short ring[36864];   // 72 KB: A[3][4096] | B[3][8192]
    __shared__ float gL[16][64];                           //  4 KB

    unsigned short* Aslot = ring;
    unsigned short* Bslot = ring + 12288;

    int b0 = blockIdx.x * 64;
    int t = threadIdx.x, w = t >> 6, lane = t & 63;
    int col = lane & 15, quad = lane >> 4;
    int wm = (w & 1) * 32, wn = (w >> 1) * 32;

    if (t < 256) {
        int te = t >> 4, r4 = (t & 15) * 4;
        *(float4_t*)&gL[te][r4] = *(const float4_t*)&gates[(size_t)te * B_ + b0 + r4];
    }

    int rowA = t >> 3;
    int csw  = ((t & 7) ^ (rowA & 7)) * 8;
    int ldsw = w * 512;

    float4_t tw0[2][2], tw1[2][2];
#pragma unroll
    for (int mi = 0; mi < 2; ++mi)
#pragma unroll
        for (int ni = 0; ni < 2; ++ni) {
            tw0[mi][ni] = (float4_t){0.f, 0.f, 0.f, 0.f};
            tw1[mi][ni] = (float4_t){0.f, 0.f, 0.f, 0.f};
        }

    auto stage = [&](int cid, int slot) {
        int ee = cid >> 2, kc = cid & 3;
        const unsigned short* hE = h + ((size_t)ee * B_ + b0 + rowA) * H1_ + kc * 64 + csw;
        async_copy16(hE, Aslot + slot * 4096 + ldsw);
        const unsigned short* wE = w2t + ((size_t)ee * H2_ + rowA) * H1_ + kc * 64 + csw;
        async_copy16(wE, Bslot + slot * 8192 + ldsw);
        async_copy16(wE + (size_t)64 * H1_, Bslot + slot * 8192 + 4096 + ldsw);
    };

    stage(0, 0);

    float4_t acc[2][2];
    int rd = 0, wr = 1;
#pragma unroll 1
    for (int cid = 0; cid < 32; ++cid) {
        if (cid < 31) {
            stage(cid + 1, wr);
            asm volatile("s_waitcnt vmcnt(3)" ::: "memory");
        } else {
            asm volatile("s_waitcnt vmcnt(0)" ::: "memory");
        }
        asm volatile("s_barrier" ::: "memory");

        if ((cid & 3) == 0) {
#pragma unroll
            for (int mi = 0; mi < 2; ++mi)
#pragma unroll
                for (int ni = 0; ni < 2; ++ni)
                    acc[mi][ni] = (float4_t){0.f, 0.f, 0.f, 0.f};
        }
        const unsigned short* Ac = Aslot + rd * 4096;
        const unsigned short* Bc = Bslot + rd * 8192;
#pragma unroll
        for (int kq = 0; kq < 2; ++kq) {
            int q = kq * 4 + quad;
            short8 af[2], bfv[2];
#pragma unroll
            for (int mi = 0; mi < 2; ++mi) {
                int r = wm + mi * 16 + col;
                af[mi] = *(const short8*)&Ac[r * 64 + ((q ^ (r & 7)) << 3)];
            }
#pragma unroll
            for (int ni = 0; ni < 2; ++ni) {
                int n = wn + ni * 16 + col;
                bfv[ni] = *(const short8*)&Bc[n * 64 + ((q ^ (n & 7)) << 3)];
            }
            __builtin_amdgcn_s_setprio(1);
#pragma unroll
            for (int mi = 0; mi < 2; ++mi)
#pragma unroll
                for (int ni = 0; ni < 2; ++ni)
                    acc[mi][ni] = __builtin_amdgcn_mfma_f32_16x16x32_bf16(
                        af[mi], bfv[ni], acc[mi][ni], 0, 0, 0);
            __builtin_amdgcn_s_setprio(0);
        }

        if ((cid & 3) == 3) {
            int ee = cid >> 2;
#pragma unroll
            for (int ni = 0; ni < 2; ++ni) {
                float bv = b2[ee * H2_ + wn + ni * 16 + col];
#pragma unroll
                for (int mi = 0; mi < 2; ++mi) {
#pragma unroll
                    for (int p = 0; p < 4; ++p) {
                        int rloc = wm + mi * 16 + quad * 4 + p;
                        float v = acc[mi][ni][p] + bv;
                        v = v > 0.f ? v : 0.f;
                        tw0[mi][ni][p] += gL[ee][rloc] * v;
                        tw1[mi][ni][p] += gL[8 + ee][rloc] * v;
                    }
                }
            }
        }
        rd = (rd == 2) ? 0 : rd + 1;
        wr = (wr == 2) ? 0 : wr + 1;
    }

#pragma unroll
    for (int mi = 0; mi < 2; ++mi) {
#pragma unroll
        for (int ni = 0; ni < 2; ++ni) {
            int n = wn + ni * 16 + col;
#pragma unroll
            for (int p = 0; p < 4; ++p) {
                int r = b0 + wm + mi * 16 + quad * 4 + p;
                out[(size_t)r * H2_ + n] = tw0[mi][ni][p];
                out[(size_t)B_ * H2_ + (size_t)r * H2_ + n] = tw1[mi][ni][p];
            }
        }
    }
}

extern "C" void kernel_launch(void* const* d_in, const int* in_sizes, int n_in,
                              void* d_out, int out_size, void* d_ws, size_t ws_size,
                              hipStream_t stream) {
    const float* x  = (const float*)d_in[0];
    const float* W1 = (const float*)d_in[1];
    const float* b1 = (const float*)d_in[2];
    const float* W2 = (const float*)d_in[3];
    const float* b2 = (const float*)d_in[4];
    const float* Wg = (const float*)d_in[5];
    const float* bg = (const float*)d_in[6];
    float* out = (float*)d_out;

    char* ws = (char*)d_ws;
    unsigned short* xb    = (unsigned short*)(ws);                // 16,777,216 B
    unsigned short* w1t   = (unsigned short*)(ws + 16777216);     //  2,097,152 B
    unsigned short* w2t   = (unsigned short*)(ws + 18874368);     //    524,288 B
    float*          gates = (float*)(ws + 19398656);              //  1,048,576 B  [16][B]
    unsigned short* h     = (unsigned short*)(ws + 20447232);     // 67,108,864 B
    // total: 87,556,096 B

    // dispatch 1: all prep + gates (x->bf16, W1^T, W2^T, gate softmax)
    prep_gates_kernel<<<dim3(2304), 256, 0, stream>>>(x, xb, W1, w1t, W2, w2t, Wg, bg, gates);

    // dispatch 2: layer 1: h[e] = relu(xb * w1t[e]^T + b1[e])   M=B, N=H1, K=I
    gemm_relu_kernel<<<dim3(B_ / 128, H1_ / 128, E_), 256, 0, stream>>>(
        xb, 0, w1t, (size_t)H1_ * I_, b1, H1_, h, (size_t)B_ * H1_, I_, I_, I_, H1_);

    // dispatch 3: fused layer 2 + gated combine, ring-3 depth-1, 2 blocks/CU
    fused_l2_combine_kernel<<<dim3(B_ / 64), 512, 0, stream>>>(h, w2t, b2, gates, out);
}

// Round 8
// 158.891 us; speedup vs baseline: 1.5786x; 1.5786x over previous
//
#include <hip/hip_runtime.h>
#include <hip/hip_bf16.h>

#define B_  16384
#define I_  512
#define H1_ 256
#define H2_ 128
#define E_  8
#define T_  2

typedef __attribute__((ext_vector_type(8))) short short8;
typedef __attribute__((ext_vector_type(4))) float float4_t;

__device__ inline unsigned short f2bf(float f) {
    union { float f; unsigned u; } v; v.f = f;
    unsigned r = v.u + 0x7FFFu + ((v.u >> 16) & 1u);
    return (unsigned short)(r >> 16);
}

// async global->LDS, 16B per lane. LDS dest = wave-uniform base + lane*16.
__device__ inline void async_copy16(const unsigned short* g, unsigned short* l) {
    __builtin_amdgcn_global_load_lds(
        (const __attribute__((address_space(1))) void*)g,
        (__attribute__((address_space(3))) void*)l,
        16, 0, 0);
}

// ================= prep + gates megakernel (one dispatch) =================
// Verified r6 version (float4 Wg staging).
__global__ void prep_gates_kernel(const float* __restrict__ x,
                                  unsigned short* __restrict__ xb,
                                  const float* __restrict__ W1,
                                  unsigned short* __restrict__ w1t,
                                  const float* __restrict__ W2,
                                  unsigned short* __restrict__ w2t,
                                  const float* __restrict__ Wg,
                                  const float* __restrict__ bg,
                                  float* __restrict__ gates) {
    __shared__ __align__(16) char smem[16 * 520 * 2 + 4 * 16 * 16 * 4];  // 20.6 KB
    int bid = blockIdx.x;
    int t = threadIdx.x;

    if (bid < 1024) {
        unsigned short* wgtL = (unsigned short*)smem;          // [16][520] padded
        float (*red)[16][16] = (float (*)[16][16])(smem + 16 * 520 * 2);
#pragma unroll
        for (int j = 0; j < 8; ++j) {
            int idx4 = j * 256 + t;                 // 0..2047 float4s of Wg
            float4_t wv = ((const float4_t*)Wg)[idx4];
            int e0   = (idx4 & 1) * 4;
            int i    = (idx4 >> 1) & 511;
            int task = idx4 >> 10;
#pragma unroll
            for (int c = 0; c < 4; ++c)
                wgtL[(task * 8 + e0 + c) * 520 + i] = f2bf(wv[c]);
        }
        __syncthreads();

        int w = t >> 6, lane = t & 63;
        int col = lane & 15, quad = lane >> 4;
        int b0 = bid * 16;
        int k0 = w * 128;
        const float* xr = x + (size_t)(b0 + col) * I_ + k0 + quad * 8;
        unsigned short* xw = xb + (size_t)(b0 + col) * I_ + k0 + quad * 8;
        const unsigned short* bL = &wgtL[col * 520 + k0 + quad * 8];
        float4_t acc = {0.f, 0.f, 0.f, 0.f};
#pragma unroll
        for (int ks = 0; ks < 128; ks += 32) {
            float4_t xa = *(const float4_t*)(xr + ks);
            float4_t xc = *(const float4_t*)(xr + ks + 4);
            short8 a;
            a[0] = (short)f2bf(xa[0]); a[1] = (short)f2bf(xa[1]);
            a[2] = (short)f2bf(xa[2]); a[3] = (short)f2bf(xa[3]);
            a[4] = (short)f2bf(xc[0]); a[5] = (short)f2bf(xc[1]);
            a[6] = (short)f2bf(xc[2]); a[7] = (short)f2bf(xc[3]);
            *(short8*)(xw + ks) = a;
            short8 b = *(const short8*)(bL + ks);
            acc = __builtin_amdgcn_mfma_f32_16x16x32_bf16(a, b, acc, 0, 0, 0);
        }
#pragma unroll
        for (int p = 0; p < 4; ++p)
            red[w][quad * 4 + p][col] = acc[p];
        __syncthreads();
        int r = t >> 4, te = t & 15;
        float v = red[0][r][te] + red[1][r][te] + red[2][r][te] + red[3][r][te] + bg[te];
        float m = v;
        m = fmaxf(m, __shfl_xor(m, 1));
        m = fmaxf(m, __shfl_xor(m, 2));
        m = fmaxf(m, __shfl_xor(m, 4));
        float ev = __expf(v - m);
        float s = ev;
        s += __shfl_xor(s, 1);
        s += __shfl_xor(s, 2);
        s += __shfl_xor(s, 4);
        gates[(size_t)te * B_ + b0 + r] = ev / s;
    } else {
        float (*tile)[33] = (float (*)[33])smem;
        const float* in; unsigned short* outp; int R, C, e, r0, c0;
        if (bid < 2048) {
            int tl = bid - 1024;               // 8 e x 16 rblk x 8 cblk
            e = tl >> 7; int rem = tl & 127;
            R = I_; C = H1_;
            r0 = (rem >> 3) * 32; c0 = (rem & 7) * 32;
            in = W1; outp = w1t;
        } else {
            int tl = bid - 2048;               // 8 e x 8 rblk x 4 cblk
            e = tl >> 5; int rem = tl & 31;
            R = H1_; C = H2_;
            r0 = (rem >> 2) * 32; c0 = (rem & 3) * 32;
            in = W2; outp = w2t;
        }
        const float* inp = in + (size_t)e * R * C;
        unsigned short* op = outp + (size_t)e * R * C;
        int tx = t & 31, ty = t >> 5;          // (32, 8)
#pragma unroll
        for (int j = 0; j < 32; j += 8)
            tile[ty + j][tx] = inp[(size_t)(r0 + ty + j) * C + c0 + tx];
        __syncthreads();
#pragma unroll
        for (int j = 0; j < 32; j += 8)
            op[(size_t)(c0 + ty + j) * R + r0 + tx] = f2bf(tile[tx][ty + j]);
    }
}

// ---------------- layer 1 grouped GEMM: h[e] = relu(xb * w1t[e]^T + b1[e]) bf16 ----------------
// r0's verified inner loop / fragments / swizzle, widened to a 128x256 tile
// (full N) with 512 threads / 8 waves. Per-wave work identical to r0 (64x64
// out, acc[4][4]). Gains: A-staging halves (xb slab staged once, not per
// n-block), blocks 2048->1024 (half the full-drain prologues per CU). LDS
// 48 KB -> 2 blocks/CU; regs 64 VGPR + 64 AGPR = 128/wave x 4 waves/SIMD =
// exactly the 512 pool (NO forced occupancy bound - r6 lesson: launch_bounds
// below register demand spills acc to scratch).
__global__ __launch_bounds__(512, 2)
void gemm_relu_kernel(const unsigned short* __restrict__ A, size_t aSE,
                      const unsigned short* __restrict__ Bt, size_t bSE,
                      const float* __restrict__ bias, int biasSE,
                      unsigned short* __restrict__ C, size_t cSE,
                      int K, int lda, int ldb, int ldc) {
    __shared__ __align__(16) unsigned short smem[24576];   // 48 KB: As | Bs
    unsigned short* As = smem;                    // 128 rows x 64 k
    unsigned short* Bs = smem + 8192;             // 256 rows x 64 k
    int e = blockIdx.z;
    const unsigned short* Ae = A + (size_t)e * aSE;
    const unsigned short* Be = Bt + (size_t)e * bSE;
    const float* biasE = bias + (size_t)e * biasSE;
    unsigned short* Ce = C + (size_t)e * cSE;
    int m0 = blockIdx.x * 128;                    // n0 = 0 (full N per block)
    int t = threadIdx.x, w = t >> 6, lane = t & 63;
    int col = lane & 15, quad = lane >> 4;
    int wm = (w & 1) * 64, wn = (w >> 1) * 64;    // wn in {0,64,128,192}

    float4_t acc[4][4];
#pragma unroll
    for (int mi = 0; mi < 4; ++mi)
#pragma unroll
        for (int ni = 0; ni < 4; ++ni)
            acc[mi][ni] = (float4_t){0.f, 0.f, 0.f, 0.f};

    // staging: one issue = 512 threads x 16 B = 64 rows x 64 k (8 KB).
    // thread row rT, swizzled source chunk gk (key = dest row & 7; rows within
    // an issue group differ by 64, so row&7 == rT&7 for all issues).
    int rT = t >> 3;                                   // 0..63
    int gk = ((t & 7) ^ (rT & 7)) * 8;
    const unsigned short* aG = Ae + (size_t)(m0 + rT) * lda + gk;
    const unsigned short* bG = Be + (size_t)rT * ldb + gk;

    for (int k0 = 0; k0 < K; k0 += 64) {
#pragma unroll
        for (int j = 0; j < 2; ++j)       // A: 128 rows
            async_copy16(aG + (size_t)j * 64 * lda + k0, As + j * 4096 + w * 512);
#pragma unroll
        for (int j = 0; j < 4; ++j)       // B: 256 rows
            async_copy16(bG + (size_t)j * 64 * ldb + k0, Bs + j * 4096 + w * 512);
        __syncthreads();
#pragma unroll
        for (int kk = 0; kk < 64; kk += 32) {
            int q = (kk >> 3) + quad;
            short8 af[4], bf[4];
#pragma unroll
            for (int mi = 0; mi < 4; ++mi) {
                int r = wm + mi * 16 + col;
                af[mi] = *(const short8*)&As[r * 64 + ((q ^ (r & 7)) * 8)];
            }
#pragma unroll
            for (int ni = 0; ni < 4; ++ni) {
                int n = wn + ni * 16 + col;
                bf[ni] = *(const short8*)&Bs[n * 64 + ((q ^ (n & 7)) * 8)];
            }
#pragma unroll
            for (int mi = 0; mi < 4; ++mi)
#pragma unroll
                for (int ni = 0; ni < 4; ++ni)
                    acc[mi][ni] = __builtin_amdgcn_mfma_f32_16x16x32_bf16(af[mi], bf[ni], acc[mi][ni], 0, 0, 0);
        }
        __syncthreads();
    }

    // epilogue: bias+relu -> bf16 in two 64-row half-passes (Ct aliases smem,
    // safe after the loop's final barrier). Waves with (w&1)==half own rows
    // half*64..+63 across all 256 cols (wn spans the full N).
    unsigned short* Ct = smem;   // 64 rows x stride 264 = 33.8 KB
#pragma unroll
    for (int half = 0; half < 2; ++half) {
        if ((w & 1) == half) {
#pragma unroll
            for (int ni = 0; ni < 4; ++ni) {
                int c = wn + ni * 16 + col;
                float bv = biasE[c];
#pragma unroll
                for (int mi = 0; mi < 4; ++mi) {
                    int rl = mi * 16 + quad * 4;     // local row within the half
#pragma unroll
                    for (int p = 0; p < 4; ++p) {
                        float v = acc[mi][ni][p] + bv;
                        v = v > 0.f ? v : 0.f;
                        Ct[(rl + p) * 264 + c] = f2bf(v);
                    }
                }
            }
        }
        __syncthreads();
#pragma unroll
        for (int j = 0; j < 4; ++j) {
            int idx = j * 512 + t;                   // 64 rows x 32 chunks
            int row = idx >> 5, cc = idx & 31;
            short8 vv = *(const short8*)&Ct[row * 264 + cc * 8];
            *(short8*)&Ce[(size_t)(m0 + half * 64 + row) * ldc + cc * 8] = vv;
        }
        __syncthreads();
    }
}

// ---------------- fused layer2 + gated combine: ring-3, depth-1 prefetch ----------------
// UNCHANGED (verified r4/r5). 64 rows x full H2 per block, grid 256, 76 KB -> 2 blocks/CU.
// Per chunk cid: [stage(cid+1) -> slot (cid+1)%3] [vmcnt(3)] [s_barrier] [compute slot cid%3]
// Race-free (R=3 >= D+2 with D=1).
__global__ __launch_bounds__(512, 4)
void fused_l2_combine_kernel(const unsigned short* __restrict__ h,
                             const unsigned short* __restrict__ w2t,
                             const float* __restrict__ b2,
                             const float* __restrict__ gates,
                             float* __restrict__ out) {
    __shared__ __align__(16) unsigned short ring[36864];   // 72 KB: A[3][4096] | B[3][8192]
    __shared__ float gL[16][64];                           //  4 KB

    unsigned short* Aslot = ring;
    unsigned short* Bslot = ring + 12288;

    int b0 = blockIdx.x * 64;
    int t = threadIdx.x, w = t >> 6, lane = t & 63;
    int col = lane & 15, quad = lane >> 4;
    int wm = (w & 1) * 32, wn = (w >> 1) * 32;

    if (t < 256) {
        int te = t >> 4, r4 = (t & 15) * 4;
        *(float4_t*)&gL[te][r4] = *(const float4_t*)&gates[(size_t)te * B_ + b0 + r4];
    }

    int rowA = t >> 3;
    int csw  = ((t & 7) ^ (rowA & 7)) * 8;
    int ldsw = w * 512;

    float4_t tw0[2][2], tw1[2][2];
#pragma unroll
    for (int mi = 0; mi < 2; ++mi)
#pragma unroll
        for (int ni = 0; ni < 2; ++ni) {
            tw0[mi][ni] = (float4_t){0.f, 0.f, 0.f, 0.f};
            tw1[mi][ni] = (float4_t){0.f, 0.f, 0.f, 0.f};
        }

    auto stage = [&](int cid, int slot) {
        int ee = cid >> 2, kc = cid & 3;
        const unsigned short* hE = h + ((size_t)ee * B_ + b0 + rowA) * H1_ + kc * 64 + csw;
        async_copy16(hE, Aslot + slot * 4096 + ldsw);
        const unsigned short* wE = w2t + ((size_t)ee * H2_ + rowA) * H1_ + kc * 64 + csw;
        async_copy16(wE, Bslot + slot * 8192 + ldsw);
        async_copy16(wE + (size_t)64 * H1_, Bslot + slot * 8192 + 4096 + ldsw);
    };

    stage(0, 0);

    float4_t acc[2][2];
    int rd = 0, wr = 1;
#pragma unroll 1
    for (int cid = 0; cid < 32; ++cid) {
        if (cid < 31) {
            stage(cid + 1, wr);
            asm volatile("s_waitcnt vmcnt(3)" ::: "memory");
        } else {
            asm volatile("s_waitcnt vmcnt(0)" ::: "memory");
        }
        asm volatile("s_barrier" ::: "memory");

        if ((cid & 3) == 0) {
#pragma unroll
            for (int mi = 0; mi < 2; ++mi)
#pragma unroll
                for (int ni = 0; ni < 2; ++ni)
                    acc[mi][ni] = (float4_t){0.f, 0.f, 0.f, 0.f};
        }
        const unsigned short* Ac = Aslot + rd * 4096;
        const unsigned short* Bc = Bslot + rd * 8192;
#pragma unroll
        for (int kq = 0; kq < 2; ++kq) {
            int q = kq * 4 + quad;
            short8 af[2], bfv[2];
#pragma unroll
            for (int mi = 0; mi < 2; ++mi) {
                int r = wm + mi * 16 + col;
                af[mi] = *(const short8*)&Ac[r * 64 + ((q ^ (r & 7)) << 3)];
            }
#pragma unroll
            for (int ni = 0; ni < 2; ++ni) {
                int n = wn + ni * 16 + col;
                bfv[ni] = *(const short8*)&Bc[n * 64 + ((q ^ (n & 7)) << 3)];
            }
            __builtin_amdgcn_s_setprio(1);
#pragma unroll
            for (int mi = 0; mi < 2; ++mi)
#pragma unroll
                for (int ni = 0; ni < 2; ++ni)
                    acc[mi][ni] = __builtin_amdgcn_mfma_f32_16x16x32_bf16(
                        af[mi], bfv[ni], acc[mi][ni], 0, 0, 0);
            __builtin_amdgcn_s_setprio(0);
        }

        if ((cid & 3) == 3) {
            int ee = cid >> 2;
#pragma unroll
            for (int ni = 0; ni < 2; ++ni) {
                float bv = b2[ee * H2_ + wn + ni * 16 + col];
#pragma unroll
                for (int mi = 0; mi < 2; ++mi) {
#pragma unroll
                    for (int p = 0; p < 4; ++p) {
                        int rloc = wm + mi * 16 + quad * 4 + p;
                        float v = acc[mi][ni][p] + bv;
                        v = v > 0.f ? v : 0.f;
                        tw0[mi][ni][p] += gL[ee][rloc] * v;
                        tw1[mi][ni][p] += gL[8 + ee][rloc] * v;
                    }
                }
            }
        }
        rd = (rd == 2) ? 0 : rd + 1;
        wr = (wr == 2) ? 0 : wr + 1;
    }

#pragma unroll
    for (int mi = 0; mi < 2; ++mi) {
#pragma unroll
        for (int ni = 0; ni < 2; ++ni) {
            int n = wn + ni * 16 + col;
#pragma unroll
            for (int p = 0; p < 4; ++p) {
                int r = b0 + wm + mi * 16 + quad * 4 + p;
                out[(size_t)r * H2_ + n] = tw0[mi][ni][p];
                out[(size_t)B_ * H2_ + (size_t)r * H2_ + n] = tw1[mi][ni][p];
            }
        }
    }
}

extern "C" void kernel_launch(void* const* d_in, const int* in_sizes, int n_in,
                              void* d_out, int out_size, void* d_ws, size_t ws_size,
                              hipStream_t stream) {
    const float* x  = (const float*)d_in[0];
    const float* W1 = (const float*)d_in[1];
    const float* b1 = (const float*)d_in[2];
    const float* W2 = (const float*)d_in[3];
    const float* b2 = (const float*)d_in[4];
    const float* Wg = (const float*)d_in[5];
    const float* bg = (const float*)d_in[6];
    float* out = (float*)d_out;

    char* ws = (char*)d_ws;
    unsigned short* xb    = (unsigned short*)(ws);                // 16,777,216 B
    unsigned short* w1t   = (unsigned short*)(ws + 16777216);     //  2,097,152 B
    unsigned short* w2t   = (unsigned short*)(ws + 18874368);     //    524,288 B
    float*          gates = (float*)(ws + 19398656);              //  1,048,576 B  [16][B]
    unsigned short* h     = (unsigned short*)(ws + 20447232);     // 67,108,864 B
    // total: 87,556,096 B

    // dispatch 1: all prep + gates (x->bf16, W1^T, W2^T, gate softmax)
    prep_gates_kernel<<<dim3(2304), 256, 0, stream>>>(x, xb, W1, w1t, W2, w2t, Wg, bg, gates);

    // dispatch 2: layer 1: 128x256 tile (full N), 512 threads, 1024 blocks
    gemm_relu_kernel<<<dim3(B_ / 128, 1, E_), 512, 0, stream>>>(
        xb, 0, w1t, (size_t)H1_ * I_, b1, H1_, h, (size_t)B_ * H1_, I_, I_, I_, H1_);

    // dispatch 3: fused layer 2 + gated combine, ring-3 depth-1, 2 blocks/CU
    fused_l2_combine_kernel<<<dim3(B_ / 64), 512, 0, stream>>>(h, w2t, b2, gates, out);
}

// Round 9
// 158.561 us; speedup vs baseline: 1.5819x; 1.0021x over previous
//
#include <hip/hip_runtime.h>
#include <hip/hip_bf16.h>

#define B_  16384
#define I_  512
#define H1_ 256
#define H2_ 128
#define E_  8
#define T_  2

typedef __attribute__((ext_vector_type(8))) short short8;
typedef __attribute__((ext_vector_type(4))) float float4_t;

__device__ inline unsigned short f2bf(float f) {
    union { float f; unsigned u; } v; v.f = f;
    unsigned r = v.u + 0x7FFFu + ((v.u >> 16) & 1u);
    return (unsigned short)(r >> 16);
}

// async global->LDS, 16B per lane. LDS dest = wave-uniform base + lane*16.
__device__ inline void async_copy16(const unsigned short* g, unsigned short* l) {
    __builtin_amdgcn_global_load_lds(
        (const __attribute__((address_space(1))) void*)g,
        (__attribute__((address_space(3))) void*)l,
        16, 0, 0);
}

// ================= prep + gates megakernel (one dispatch) =================
// Gates blocks now process 64 rows each (256 blocks instead of 1024):
// each wave owns 16 rows x full K=512 with a private MFMA accumulator ->
// Wg staging amortized 4x, no cross-wave LDS reduction, one barrier.
// Softmax mapping identical to the verified original: te = lane&15 (col of
// C), local m-row = quad*4+p; expert-reduce via shfl_xor(1,2,4) within the
// 8-lane e-group (softmax is over E=8 within each task).
__global__ void prep_gates_kernel(const float* __restrict__ x,
                                  unsigned short* __restrict__ xb,
                                  const float* __restrict__ W1,
                                  unsigned short* __restrict__ w1t,
                                  const float* __restrict__ W2,
                                  unsigned short* __restrict__ w2t,
                                  const float* __restrict__ Wg,
                                  const float* __restrict__ bg,
                                  float* __restrict__ gates) {
    __shared__ __align__(16) char smem[16 * 520 * 2 + 4 * 16 * 16 * 4];  // 20.6 KB
    int bid = blockIdx.x;
    int t = threadIdx.x;

    if (bid < 256) {
        unsigned short* wgtL = (unsigned short*)smem;          // [16][520] padded
#pragma unroll
        for (int j = 0; j < 8; ++j) {
            int idx4 = j * 256 + t;                 // 0..2047 float4s of Wg
            float4_t wv = ((const float4_t*)Wg)[idx4];
            int e0   = (idx4 & 1) * 4;
            int i    = (idx4 >> 1) & 511;
            int task = idx4 >> 10;
#pragma unroll
            for (int c = 0; c < 4; ++c)
                wgtL[(task * 8 + e0 + c) * 520 + i] = f2bf(wv[c]);
        }
        __syncthreads();

        int w = t >> 6, lane = t & 63;
        int col = lane & 15, quad = lane >> 4;
        int row = bid * 64 + w * 16 + col;          // this wave's A-row
        const float* xr = x + (size_t)row * I_ + quad * 8;
        unsigned short* xw = xb + (size_t)row * I_ + quad * 8;
        const unsigned short* bL = &wgtL[col * 520 + quad * 8];
        float4_t acc = {0.f, 0.f, 0.f, 0.f};
#pragma unroll
        for (int ks = 0; ks < 512; ks += 32) {
            float4_t xa = *(const float4_t*)(xr + ks);
            float4_t xc = *(const float4_t*)(xr + ks + 4);
            short8 a;
            a[0] = (short)f2bf(xa[0]); a[1] = (short)f2bf(xa[1]);
            a[2] = (short)f2bf(xa[2]); a[3] = (short)f2bf(xa[3]);
            a[4] = (short)f2bf(xc[0]); a[5] = (short)f2bf(xc[1]);
            a[6] = (short)f2bf(xc[2]); a[7] = (short)f2bf(xc[3]);
            *(short8*)(xw + ks) = a;
            short8 b = *(const short8*)(bL + ks);
            acc = __builtin_amdgcn_mfma_f32_16x16x32_bf16(a, b, acc, 0, 0, 0);
        }
        // per-lane: acc[p] = logits[local row quad*4+p][te=col]
        float g[4];
#pragma unroll
        for (int p = 0; p < 4; ++p) {
            float v = acc[p] + bg[col];
            float m = v;
            m = fmaxf(m, __shfl_xor(m, 1));
            m = fmaxf(m, __shfl_xor(m, 2));
            m = fmaxf(m, __shfl_xor(m, 4));
            float ev = __expf(v - m);
            float s = ev;
            s += __shfl_xor(s, 1);
            s += __shfl_xor(s, 2);
            s += __shfl_xor(s, 4);
            g[p] = ev / s;
        }
#pragma unroll
        for (int p = 0; p < 4; ++p)
            gates[(size_t)col * B_ + bid * 64 + w * 16 + quad * 4 + p] = g[p];
    } else {
        float (*tile)[33] = (float (*)[33])smem;
        const float* in; unsigned short* outp; int R, C, e, r0, c0;
        if (bid < 1280) {
            int tl = bid - 256;                // 8 e x 16 rblk x 8 cblk = 1024
            e = tl >> 7; int rem = tl & 127;
            R = I_; C = H1_;
            r0 = (rem >> 3) * 32; c0 = (rem & 7) * 32;
            in = W1; outp = w1t;
        } else {
            int tl = bid - 1280;               // 8 e x 8 rblk x 4 cblk = 256
            e = tl >> 5; int rem = tl & 31;
            R = H1_; C = H2_;
            r0 = (rem >> 2) * 32; c0 = (rem & 3) * 32;
            in = W2; outp = w2t;
        }
        const float* inp = in + (size_t)e * R * C;
        unsigned short* op = outp + (size_t)e * R * C;
        int tx = t & 31, ty = t >> 5;          // (32, 8)
#pragma unroll
        for (int j = 0; j < 32; j += 8)
            tile[ty + j][tx] = inp[(size_t)(r0 + ty + j) * C + c0 + tx];
        __syncthreads();
#pragma unroll
        for (int j = 0; j < 32; j += 8)
            op[(size_t)(c0 + ty + j) * R + r0 + tx] = f2bf(tile[tx][ty + j]);
    }
}

// ---------------- layer 1 grouped GEMM: h[e] = relu(xb * w1t[e]^T + b1[e]) bf16 ----------------
// VERBATIM r0 (proven 49.7 us): 128x128 tile, 256 threads, 4 blocks/CU,
// LDS 34816 B (As|Bs aliased by padded C-tile in the epilogue).
__global__ void gemm_relu_kernel(const unsigned short* __restrict__ A, size_t aSE,
                                 const unsigned short* __restrict__ Bt, size_t bSE,
                                 const float* __restrict__ bias, int biasSE,
                                 unsigned short* __restrict__ C, size_t cSE,
                                 int K, int lda, int ldb, int ldc) {
    __shared__ unsigned short smem[128 * 136];   // 34 KB: As|Bs, aliased by padded C-tile
    unsigned short* As = smem;                    // 128*64
    unsigned short* Bs = smem + 128 * 64;         // 128*64
    int e = blockIdx.z;
    const unsigned short* Ae = A + (size_t)e * aSE;
    const unsigned short* Be = Bt + (size_t)e * bSE;
    const float* biasE = bias + (size_t)e * biasSE;
    unsigned short* Ce = C + (size_t)e * cSE;
    int m0 = blockIdx.x * 128, n0 = blockIdx.y * 128;
    int t = threadIdx.x, w = t >> 6, lane = t & 63;
    int col = lane & 15, quad = lane >> 4;
    int wm = (w & 1) * 64, wn = (w >> 1) * 64;

    float4_t acc[4][4];
#pragma unroll
    for (int mi = 0; mi < 4; ++mi)
#pragma unroll
        for (int ni = 0; ni < 4; ++ni)
            acc[mi][ni] = (float4_t){0.f, 0.f, 0.f, 0.f};

    int rT = t >> 3;
    int gk = (((t & 7) ^ (rT & 7))) * 8;
    const unsigned short* aG = Ae + (size_t)(m0 + rT) * lda + gk;
    const unsigned short* bG = Be + (size_t)(n0 + rT) * ldb + gk;
    unsigned short* aL = As + (size_t)w * 64 * 8;
    unsigned short* bL = Bs + (size_t)w * 64 * 8;

    for (int k0 = 0; k0 < K; k0 += 64) {
#pragma unroll
        for (int j = 0; j < 4; ++j) {
            async_copy16(aG + (size_t)j * 32 * lda + k0, aL + j * 2048);
            async_copy16(bG + (size_t)j * 32 * ldb + k0, bL + j * 2048);
        }
        __syncthreads();
#pragma unroll
        for (int kk = 0; kk < 64; kk += 32) {
            int q = (kk >> 3) + quad;
            short8 af[4], bf[4];
#pragma unroll
            for (int mi = 0; mi < 4; ++mi) {
                int r = wm + mi * 16 + col;
                af[mi] = *(const short8*)&As[r * 64 + ((q ^ (r & 7)) * 8)];
            }
#pragma unroll
            for (int ni = 0; ni < 4; ++ni) {
                int r = wn + ni * 16 + col;
                bf[ni] = *(const short8*)&Bs[r * 64 + ((q ^ (r & 7)) * 8)];
            }
#pragma unroll
            for (int mi = 0; mi < 4; ++mi)
#pragma unroll
                for (int ni = 0; ni < 4; ++ni)
                    acc[mi][ni] = __builtin_amdgcn_mfma_f32_16x16x32_bf16(af[mi], bf[ni], acc[mi][ni], 0, 0, 0);
        }
        __syncthreads();
    }
    // after final barrier all LDS reads are done -> safe to alias as padded C-tile
    unsigned short* Ct = smem;   // 128 rows x stride 136
#pragma unroll
    for (int ni = 0; ni < 4; ++ni) {
        int c = wn + ni * 16 + col;
        float bv = biasE[n0 + c];
#pragma unroll
        for (int mi = 0; mi < 4; ++mi) {
            int rbase = wm + mi * 16 + quad * 4;
#pragma unroll
            for (int p = 0; p < 4; ++p) {
                float v = acc[mi][ni][p] + bv;
                v = v > 0.f ? v : 0.f;
                Ct[(rbase + p) * 136 + c] = f2bf(v);
            }
        }
    }
    __syncthreads();
    int rr = t >> 4, sl = t & 15;
#pragma unroll
    for (int pass = 0; pass < 8; ++pass) {
        int row = pass * 16 + rr;
        short8 vv = *(const short8*)&Ct[row * 136 + sl * 8];
        *(short8*)&Ce[(size_t)(m0 + row) * ldc + n0 + sl * 8] = vv;
    }
}

// ---------------- fused layer2 + gated combine: ring-3, depth-1 prefetch ----------------
// UNCHANGED (verified r4/r5/r8). 64 rows x full H2 per block, grid 256, 76 KB -> 2 blocks/CU.
// Per chunk cid: [stage(cid+1) -> slot (cid+1)%3] [vmcnt(3)] [s_barrier] [compute slot cid%3]
// Race-free (R=3 >= D+2 with D=1).
__global__ __launch_bounds__(512, 4)
void fused_l2_combine_kernel(const unsigned short* __restrict__ h,
                             const unsigned short* __restrict__ w2t,
                             const float* __restrict__ b2,
                             const float* __restrict__ gates,
                             float* __restrict__ out) {
    __shared__ __align__(16) unsigned short ring[36864];   // 72 KB: A[3][4096] | B[3][8192]
    __shared__ float gL[16][64];                           //  4 KB

    unsigned short* Aslot = ring;
    unsigned short* Bslot = ring + 12288;

    int b0 = blockIdx.x * 64;
    int t = threadIdx.x, w = t >> 6, lane = t & 63;
    int col = lane & 15, quad = lane >> 4;
    int wm = (w & 1) * 32, wn = (w >> 1) * 32;

    if (t < 256) {
        int te = t >> 4, r4 = (t & 15) * 4;
        *(float4_t*)&gL[te][r4] = *(const float4_t*)&gates[(size_t)te * B_ + b0 + r4];
    }

    int rowA = t >> 3;
    int csw  = ((t & 7) ^ (rowA & 7)) * 8;
    int ldsw = w * 512;

    float4_t tw0[2][2], tw1[2][2];
#pragma unroll
    for (int mi = 0; mi < 2; ++mi)
#pragma unroll
        for (int ni = 0; ni < 2; ++ni) {
            tw0[mi][ni] = (float4_t){0.f, 0.f, 0.f, 0.f};
            tw1[mi][ni] = (float4_t){0.f, 0.f, 0.f, 0.f};
        }

    auto stage = [&](int cid, int slot) {
        int ee = cid >> 2, kc = cid & 3;
        const unsigned short* hE = h + ((size_t)ee * B_ + b0 + rowA) * H1_ + kc * 64 + csw;
        async_copy16(hE, Aslot + slot * 4096 + ldsw);
        const unsigned short* wE = w2t + ((size_t)ee * H2_ + rowA) * H1_ + kc * 64 + csw;
        async_copy16(wE, Bslot + slot * 8192 + ldsw);
        async_copy16(wE + (size_t)64 * H1_, Bslot + slot * 8192 + 4096 + ldsw);
    };

    stage(0, 0);

    float4_t acc[2][2];
    int rd = 0, wr = 1;
#pragma unroll 1
    for (int cid = 0; cid < 32; ++cid) {
        if (cid < 31) {
            stage(cid + 1, wr);
            asm volatile("s_waitcnt vmcnt(3)" ::: "memory");
        } else {
            asm volatile("s_waitcnt vmcnt(0)" ::: "memory");
        }
        asm volatile("s_barrier" ::: "memory");

        if ((cid & 3) == 0) {
#pragma unroll
            for (int mi = 0; mi < 2; ++mi)
#pragma unroll
                for (int ni = 0; ni < 2; ++ni)
                    acc[mi][ni] = (float4_t){0.f, 0.f, 0.f, 0.f};
        }
        const unsigned short* Ac = Aslot + rd * 4096;
        const unsigned short* Bc = Bslot + rd * 8192;
#pragma unroll
        for (int kq = 0; kq < 2; ++kq) {
            int q = kq * 4 + quad;
            short8 af[2], bfv[2];
#pragma unroll
            for (int mi = 0; mi < 2; ++mi) {
                int r = wm + mi * 16 + col;
                af[mi] = *(const short8*)&Ac[r * 64 + ((q ^ (r & 7)) << 3)];
            }
#pragma unroll
            for (int ni = 0; ni < 2; ++ni) {
                int n = wn + ni * 16 + col;
                bfv[ni] = *(const short8*)&Bc[n * 64 + ((q ^ (n & 7)) << 3)];
            }
            __builtin_amdgcn_s_setprio(1);
#pragma unroll
            for (int mi = 0; mi < 2; ++mi)
#pragma unroll
                for (int ni = 0; ni < 2; ++ni)
                    acc[mi][ni] = __builtin_amdgcn_mfma_f32_16x16x32_bf16(
                        af[mi], bfv[ni], acc[mi][ni], 0, 0, 0);
            __builtin_amdgcn_s_setprio(0);
        }

        if ((cid & 3) == 3) {
            int ee = cid >> 2;
#pragma unroll
            for (int ni = 0; ni < 2; ++ni) {
                float bv = b2[ee * H2_ + wn + ni * 16 + col];
#pragma unroll
                for (int mi = 0; mi < 2; ++mi) {
#pragma unroll
                    for (int p = 0; p < 4; ++p) {
                        int rloc = wm + mi * 16 + quad * 4 + p;
                        float v = acc[mi][ni][p] + bv;
                        v = v > 0.f ? v : 0.f;
                        tw0[mi][ni][p] += gL[ee][rloc] * v;
                        tw1[mi][ni][p] += gL[8 + ee][rloc] * v;
                    }
                }
            }
        }
        rd = (rd == 2) ? 0 : rd + 1;
        wr = (wr == 2) ? 0 : wr + 1;
    }

#pragma unroll
    for (int mi = 0; mi < 2; ++mi) {
#pragma unroll
        for (int ni = 0; ni < 2; ++ni) {
            int n = wn + ni * 16 + col;
#pragma unroll
            for (int p = 0; p < 4; ++p) {
                int r = b0 + wm + mi * 16 + quad * 4 + p;
                out[(size_t)r * H2_ + n] = tw0[mi][ni][p];
                out[(size_t)B_ * H2_ + (size_t)r * H2_ + n] = tw1[mi][ni][p];
            }
        }
    }
}

extern "C" void kernel_launch(void* const* d_in, const int* in_sizes, int n_in,
                              void* d_out, int out_size, void* d_ws, size_t ws_size,
                              hipStream_t stream) {
    const float* x  = (const float*)d_in[0];
    const float* W1 = (const float*)d_in[1];
    const float* b1 = (const float*)d_in[2];
    const float* W2 = (const float*)d_in[3];
    const float* b2 = (const float*)d_in[4];
    const float* Wg = (const float*)d_in[5];
    const float* bg = (const float*)d_in[6];
    float* out = (float*)d_out;

    char* ws = (char*)d_ws;
    unsigned short* xb    = (unsigned short*)(ws);                // 16,777,216 B
    unsigned short* w1t   = (unsigned short*)(ws + 16777216);     //  2,097,152 B
    unsigned short* w2t   = (unsigned short*)(ws + 18874368);     //    524,288 B
    float*          gates = (float*)(ws + 19398656);              //  1,048,576 B  [16][B]
    unsigned short* h     = (unsigned short*)(ws + 20447232);     // 67,108,864 B
    // total: 87,556,096 B

    // dispatch 1: all prep + gates (x->bf16, W1^T, W2^T, gate softmax)
    // 256 gates blocks (64 rows each) + 1024 W1-transpose + 256 W2-transpose
    prep_gates_kernel<<<dim3(1536), 256, 0, stream>>>(x, xb, W1, w1t, W2, w2t, Wg, bg, gates);

    // dispatch 2: layer 1 (verbatim r0): h[e] = relu(xb * w1t[e]^T + b1[e])
    gemm_relu_kernel<<<dim3(B_ / 128, H1_ / 128, E_), 256, 0, stream>>>(
        xb, 0, w1t, (size_t)H1_ * I_, b1, H1_, h, (size_t)B_ * H1_, I_, I_, I_, H1_);

    // dispatch 3: fused layer 2 + gated combine, ring-3 depth-1, 2 blocks/CU
    fused_l2_combine_kernel<<<dim3(B_ / 64), 512, 0, stream>>>(h, w2t, b2, gates, out);
}